// Round 7
// baseline (225.370 us; speedup 1.0000x reference)
//
#include <hip/hip_runtime.h>

#define TT 3
#define CCH 32
#define HH 256
#define WW 256
#define KK 7
#define NQ 64
#define QPB 16
#define V1W 76            // y row length (qwi=15 reads dwords 60..75)
#define V1R 14
#define V1N (V1R*V1W)     // 1064 dwords per channel plane
#define V1P 1080          // padded plane stride (16B-aligned)
#define CHC 8             // channels per chunk
#define NCHUNK 4

__device__ __forceinline__ int refl(int i, int n) {
    i = i < 0 ? -i : i;
    return i >= n ? 2*(n-1) - i : i;
}

__device__ __forceinline__ void gload_lds(const float* g, float* l) {
    __builtin_amdgcn_global_load_lds(
        (const __attribute__((address_space(1))) unsigned int*)g,
        (__attribute__((address_space(3))) unsigned int*)l, 4, 0, 0);
}

__global__ __launch_bounds__(256, 3)
void nls_kernel(const float* __restrict__ vid0, const float* __restrict__ vid1,
                float* __restrict__ out) {
    __shared__ float v1s[CHC * V1P];   // 34560 B -> 3 blocks/CU

    const int bx  = blockIdx.x;
    const int t   = bx >> 8;
    const int rem = bx & 255;
    const int qy  = rem >> 2;
    const int q0  = (rem & 3) * QPB;
    const int qh  = qy * 4;
    const int w0  = 4*q0 - 7;

    const int tid   = threadIdx.x;
    const int qwi   = tid & 15;          // bits 0-3: query
    const int c01   = (tid >> 4) & 3;    // bits 4-5: channel low
    const int c2    = (tid >> 6) & 1;    // bit 6: channel high
    const int shh   = tid >> 7;          // bit 7: sh half
    const int clane = c01 + 4*c2;        // channel 0..7 within chunk
    const int qx    = q0 + qwi;

    // v1 staging offsets (channel-independent)
    int off1[5];
#pragma unroll
    for (int k = 0; k < 5; ++k) {
        int idx = tid + 256*k;
        if (idx < V1N) {
            int r = idx / V1W, wi = idx - r*V1W;
            off1[k] = refl(qh + r - 7, HH) * WW + refl(w0 + wi, WW);
        } else off1[k] = 0;
    }
    // x-patch row offsets (block-uniform, 7 rows)
    int rowoff[7];
#pragma unroll
    for (int i = 0; i < 7; ++i) rowoff[i] = refl(qh + i - 3, HH) * WW;

    float acc[4][8];
#pragma unroll
    for (int a = 0; a < 4; ++a)
#pragma unroll
        for (int b = 0; b < 8; ++b) acc[a][b] = 0.f;

    const float* g0t = vid0 + (size_t)t * (CCH*HH*WW);
    const float* g1t = vid1 + (size_t)t * (CCH*HH*WW);

#pragma unroll 1
    for (int s = 0; s < NCHUNK; ++s) {
        __syncthreads();   // previous chunk's LDS reads complete before overwrite
        // ---- async DMA: v1 chunk (8 channels) straight into LDS ----
#pragma unroll
        for (int ch = 0; ch < CHC; ++ch) {
            const float* p1 = g1t + (size_t)(CHC*s + ch) * (HH*WW);
            float* lb = &v1s[ch*V1P + (tid & ~63)];
#pragma unroll
            for (int k = 0; k < 4; ++k)
                gload_lds(p1 + off1[k], lb + 256*k);
            if (tid < V1N - 1024)
                gload_lds(p1 + off1[4], &v1s[ch*V1P + 1024 + (tid & ~63)]);
        }

        const float* p0 = g0t + (size_t)(CHC*s + clane) * (HH*WW);

        // rolling x window: 5 slots of 7 floats; load row 0 before drain
        float xw[5][7];
        auto loadx = [&](int i, float xr[7]) {
            const float* rowp = p0 + rowoff[i];
            float4 B = *(const float4*)(rowp + 4*qx);
            float4 A;
            if (qx > 0) A = *(const float4*)(rowp + 4*qx - 4);
            else        A = make_float4(0.f, B.w, B.z, B.y);   // reflect at w<0
            xr[0]=A.y; xr[1]=A.z; xr[2]=A.w;
            xr[3]=B.x; xr[4]=B.y; xr[5]=B.z; xr[6]=B.w;
        };
        loadx(0, xw[0]);

        __syncthreads();   // DMA drained

        const float* yb = &v1s[clane*V1P + 4*qwi];
        float4 yA[2][4];   // ping-pong y row buffers
        {
            const float4* yp = (const float4*)(yb + (4*shh) * V1W);
            yA[0][0]=yp[0]; yA[0][1]=yp[1]; yA[0][2]=yp[2]; yA[0][3]=yp[3];
        }

#pragma unroll
        for (int rr = 0; rr < 10; ++rr) {
            // prefetch next y row into the other buffer (covered by FMAs below)
            if (rr + 1 < 10) {
                const float4* yp = (const float4*)(yb + (4*shh + rr + 1) * V1W);
                yA[(rr+1)&1][0]=yp[0]; yA[(rr+1)&1][1]=yp[1];
                yA[(rr+1)&1][2]=yp[2]; yA[(rr+1)&1][3]=yp[3];
            }
            // prefetch next x row (global, L1/L2-resident)
            if (rr + 1 < 7) loadx(rr + 1, xw[(rr+1)%5]);

            const float4* Y = yA[rr&1];
            float y[16];
            y[0]=Y[0].x;  y[1]=Y[0].y;  y[2]=Y[0].z;  y[3]=Y[0].w;
            y[4]=Y[1].x;  y[5]=Y[1].y;  y[6]=Y[1].z;  y[7]=Y[1].w;
            y[8]=Y[2].x;  y[9]=Y[2].y;  y[10]=Y[2].z; y[11]=Y[2].w;
            y[12]=Y[3].x; y[13]=Y[3].y; y[14]=Y[3].z; y[15]=Y[3].w;
#pragma unroll
            for (int a = 0; a < 4; ++a) {
                const int pi = rr - a;              // compile-time after unroll
                if (pi >= 0 && pi < 7) {
#pragma unroll
                    for (int sw = 0; sw < 8; ++sw)
#pragma unroll
                        for (int j = 0; j < 7; ++j)
                            acc[a][sw] += xw[pi%5][j] * y[sw + j];
                }
            }
        }
    }

    // ---- reduce over c01 (lane bits 4,5) ----
#pragma unroll
    for (int m = 16; m <= 32; m <<= 1)
#pragma unroll
        for (int a = 0; a < 4; ++a)
#pragma unroll
            for (int b = 0; b < 8; ++b)
                acc[a][b] += __shfl_xor(acc[a][b], m, 64);

    __syncthreads();                 // all LDS reads done; overlay dists
    float* dlds = v1s;               // [c2][16 q][64 shifts]
    if (c01 == 0) {
#pragma unroll
        for (int a = 0; a < 4; ++a) {
            float* dp = &dlds[c2*1024 + qwi*64 + (shh*4 + a)*8];
            *(float4*)(dp)     = make_float4(acc[a][0], acc[a][1], acc[a][2], acc[a][3]);
            *(float4*)(dp + 4) = make_float4(acc[a][4], acc[a][5], acc[a][6], acc[a][7]);
        }
    }
    __syncthreads();

    // ---- top-7: 16 threads per query ----
    {
        const int q16 = tid >> 4;
        const int l16 = tid & 15;
        const float* d0 = &dlds[q16 * 64];
        const float* d1 = d0 + 1024;
        const int j0 = l16 * 4;
        float cv[4];
#pragma unroll
        for (int jj = 0; jj < 4; ++jj) {
            float v = d0[j0 + jj] + d1[j0 + jj];
            if (j0 + jj == 36) v += 1e30f;    // self bias (selection only)
            cv[jj] = v;
        }
        unsigned mask = 0;
        const int qxx = q0 + q16;
        const int q   = (t*NQ + qy)*NQ + qxx;
        float* od = out + q*KK;
        float* oi = out + (size_t)TT*NQ*NQ*KK + (size_t)q*KK*3;
        for (int k = 0; k < KK; ++k) {
            float best = -3.4e38f; int bi = 1 << 30;
#pragma unroll
            for (int jj = 0; jj < 4; ++jj)
                if (!(mask & (1u << jj)) && cv[jj] > best) { best = cv[jj]; bi = j0 + jj; }
#pragma unroll
            for (int m = 1; m <= 8; m <<= 1) {
                float ob = __shfl_xor(best, m, 64);
                int  obi = __shfl_xor(bi,  m, 64);
                if (ob > best || (ob == best && obi < bi)) { best = ob; bi = obi; }
            }
            if ((bi >> 2) == l16) mask |= 1u << (bi & 3);
            if (l16 == 0) {
                od[k] = d0[bi] + d1[bi];       // unbiased value
                int dh = (bi >> 3) - 4;
                int dw = (bi & 7) - 4;
                oi[k*3 + 0] = (float)t;
                oi[k*3 + 1] = (float)refl(qh + dh, HH);
                oi[k*3 + 2] = (float)refl(qxx*4 + dw, WW);
            }
        }
    }
}

extern "C" void kernel_launch(void* const* d_in, const int* in_sizes, int n_in,
                              void* d_out, int out_size, void* d_ws, size_t ws_size,
                              hipStream_t stream) {
    (void)in_sizes; (void)n_in; (void)d_ws; (void)ws_size; (void)out_size;
    const float* vid0 = (const float*)d_in[0];
    const float* vid1 = (const float*)d_in[1];
    float* out = (float*)d_out;
    nls_kernel<<<dim3(TT * NQ * (NQ / QPB)), dim3(256), 0, stream>>>(vid0, vid1, out);
}

// Round 8
// 123.880 us; speedup vs baseline: 1.8193x; 1.8193x over previous
//
#include <hip/hip_runtime.h>

#define TT 3
#define CCH 32
#define HH 256
#define WW 256
#define KK 7
#define NQ 64
#define QPB 16
#define V1W 76            // y row length (qwi=15 reads dwords 60..75)
#define V1R 14
#define V1N (V1R*V1W)     // 1064 dwords per channel plane
#define V1P 1088          // padded plane stride, multiple of 32 banks & 16B
#define CHC 8             // channels per chunk
#define NCHUNK 4

__device__ __forceinline__ int refl(int i, int n) {
    i = i < 0 ? -i : i;
    return i >= n ? 2*(n-1) - i : i;
}

__device__ __forceinline__ void gload_lds(const float* g, float* l) {
    __builtin_amdgcn_global_load_lds(
        (const __attribute__((address_space(1))) unsigned int*)g,
        (__attribute__((address_space(3))) unsigned int*)l, 4, 0, 0);
}

// FMA block for logical row RR (compile-time), consuming y[16] and x[7][8]
#define FMABLOCK(RR)                                                     \
    _Pragma("unroll")                                                    \
    for (int a = 0; a < 4; ++a) {                                        \
        const int pi = (RR) - a;                                         \
        if (pi >= 0 && pi < 7) {                                         \
            _Pragma("unroll")                                            \
            for (int sw = 0; sw < 8; ++sw)                               \
                _Pragma("unroll")                                        \
                for (int j = 0; j < 7; ++j)                              \
                    acc[a][sw] += x[pi][j] * y[sw + j];                  \
        }                                                                \
    }

// One row step: prefetch row RR+1 into N*, compute from C*
#define ROW(RR, C0,C1,C2v,C3v, N0,N1,N2,N3)                              \
    {                                                                    \
        if ((RR) + 1 < 10) {                                             \
            const float4* yp = (const float4*)(ybase + (4*shh + (RR) + 1) * V1W); \
            N0 = yp[0]; N1 = yp[1]; N2 = yp[2]; N3 = yp[3];              \
        }                                                                \
        const float y[16] = {C0.x,C0.y,C0.z,C0.w,  C1.x,C1.y,C1.z,C1.w,  \
                             C2v.x,C2v.y,C2v.z,C2v.w, C3v.x,C3v.y,C3v.z,C3v.w}; \
        FMABLOCK(RR)                                                     \
    }

__global__ __launch_bounds__(256, 3)
void nls_kernel(const float* __restrict__ vid0, const float* __restrict__ vid1,
                float* __restrict__ out) {
    __shared__ float v1s[CHC * V1P];   // 34816 B -> 3 blocks/CU

    const int bx  = blockIdx.x;
    const int t   = bx >> 8;
    const int rem = bx & 255;
    const int qy  = rem >> 2;
    const int q0  = (rem & 3) * QPB;
    const int qh  = qy * 4;
    const int w0  = 4*q0 - 7;

    const int tid   = threadIdx.x;
    const int qwi   = tid & 15;          // bits 0-3: query
    const int c01   = (tid >> 4) & 3;    // bits 4-5: channel low
    const int c2    = (tid >> 6) & 1;    // bit 6: channel high
    const int shh   = tid >> 7;          // bit 7: sh half
    const int clane = c01 + 4*c2;        // channel 0..7 within chunk
    const int qx    = q0 + qwi;

    // v1 staging offsets (channel-independent)
    int off1[5];
#pragma unroll
    for (int k = 0; k < 5; ++k) {
        int idx = tid + 256*k;
        if (idx < V1N) {
            int r = idx / V1W, wi = idx - r*V1W;
            off1[k] = refl(qh + r - 7, HH) * WW + refl(w0 + wi, WW);
        } else off1[k] = 0;
    }

    float acc[4][8];
#pragma unroll
    for (int a = 0; a < 4; ++a)
#pragma unroll
        for (int b = 0; b < 8; ++b) acc[a][b] = 0.f;

    const float* g0t = vid0 + (size_t)t * (CCH*HH*WW);
    const float* g1t = vid1 + (size_t)t * (CCH*HH*WW);

#pragma unroll 1
    for (int s = 0; s < NCHUNK; ++s) {
        __syncthreads();   // previous chunk's LDS reads complete before overwrite
        // ---- async DMA: v1 chunk (8 channels) straight into LDS ----
#pragma unroll
        for (int ch = 0; ch < CHC; ++ch) {
            const float* p1 = g1t + (size_t)(CHC*s + ch) * (HH*WW);
            float* lb = &v1s[ch*V1P + (tid & ~63)];
#pragma unroll
            for (int k = 0; k < 4; ++k)
                gload_lds(p1 + off1[k], lb + 256*k);
            if (tid < V1N - 1024)
                gload_lds(p1 + off1[4], &v1s[ch*V1P + 1024 + (tid & ~63)]);
        }

        // ---- x patch from global (straight-line, round-5 style) ----
        const float* p0 = g0t + (size_t)(CHC*s + clane) * (HH*WW);
        float x[7][8];
#pragma unroll
        for (int i = 0; i < 7; ++i) {
            const float* rowp = p0 + refl(qh + i - 3, HH) * WW;
            float4 B = *(const float4*)(rowp + 4*qx);
            float4 A;
            if (qx > 0) A = *(const float4*)(rowp + 4*qx - 4);
            else        A = make_float4(0.f, B.w, B.z, B.y);   // reflect at w<0
            x[i][0]=A.y; x[i][1]=A.z; x[i][2]=A.w;
            x[i][3]=B.x; x[i][4]=B.y; x[i][5]=B.z; x[i][6]=B.w;
        }
        __syncthreads();   // DMA drained

        // ---- compute with explicit y double-buffer (named registers) ----
        const float* ybase = &v1s[clane*V1P + 4*qwi];
        float4 Ya0, Ya1, Ya2, Ya3, Yb0, Yb1, Yb2, Yb3;
        {
            const float4* yp = (const float4*)(ybase + (4*shh) * V1W);
            Ya0 = yp[0]; Ya1 = yp[1]; Ya2 = yp[2]; Ya3 = yp[3];
        }
        ROW(0, Ya0,Ya1,Ya2,Ya3, Yb0,Yb1,Yb2,Yb3)
        ROW(1, Yb0,Yb1,Yb2,Yb3, Ya0,Ya1,Ya2,Ya3)
        ROW(2, Ya0,Ya1,Ya2,Ya3, Yb0,Yb1,Yb2,Yb3)
        ROW(3, Yb0,Yb1,Yb2,Yb3, Ya0,Ya1,Ya2,Ya3)
        ROW(4, Ya0,Ya1,Ya2,Ya3, Yb0,Yb1,Yb2,Yb3)
        ROW(5, Yb0,Yb1,Yb2,Yb3, Ya0,Ya1,Ya2,Ya3)
        ROW(6, Ya0,Ya1,Ya2,Ya3, Yb0,Yb1,Yb2,Yb3)
        ROW(7, Yb0,Yb1,Yb2,Yb3, Ya0,Ya1,Ya2,Ya3)
        ROW(8, Ya0,Ya1,Ya2,Ya3, Yb0,Yb1,Yb2,Yb3)
        ROW(9, Yb0,Yb1,Yb2,Yb3, Ya0,Ya1,Ya2,Ya3)
    }

    // ---- reduce over c01 (lane bits 4,5) ----
#pragma unroll
    for (int m = 16; m <= 32; m <<= 1)
#pragma unroll
        for (int a = 0; a < 4; ++a)
#pragma unroll
            for (int b = 0; b < 8; ++b)
                acc[a][b] += __shfl_xor(acc[a][b], m, 64);

    __syncthreads();                 // all LDS reads done; overlay dists
    float* dlds = v1s;               // [c2][16 q][64 shifts]
    if (c01 == 0) {
#pragma unroll
        for (int a = 0; a < 4; ++a) {
            float* dp = &dlds[c2*1024 + qwi*64 + (shh*4 + a)*8];
            *(float4*)(dp)     = make_float4(acc[a][0], acc[a][1], acc[a][2], acc[a][3]);
            *(float4*)(dp + 4) = make_float4(acc[a][4], acc[a][5], acc[a][6], acc[a][7]);
        }
    }
    __syncthreads();

    // ---- top-7: 16 threads per query ----
    {
        const int q16 = tid >> 4;
        const int l16 = tid & 15;
        const float* d0 = &dlds[q16 * 64];
        const float* d1 = d0 + 1024;
        const int j0 = l16 * 4;
        float cv[4];
#pragma unroll
        for (int jj = 0; jj < 4; ++jj) {
            float v = d0[j0 + jj] + d1[j0 + jj];
            if (j0 + jj == 36) v += 1e30f;    // self bias (selection only)
            cv[jj] = v;
        }
        unsigned mask = 0;
        const int qxx = q0 + q16;
        const int q   = (t*NQ + qy)*NQ + qxx;
        float* od = out + q*KK;
        float* oi = out + (size_t)TT*NQ*NQ*KK + (size_t)q*KK*3;
        for (int k = 0; k < KK; ++k) {
            float best = -3.4e38f; int bi = 1 << 30;
#pragma unroll
            for (int jj = 0; jj < 4; ++jj)
                if (!(mask & (1u << jj)) && cv[jj] > best) { best = cv[jj]; bi = j0 + jj; }
#pragma unroll
            for (int m = 1; m <= 8; m <<= 1) {
                float ob = __shfl_xor(best, m, 64);
                int  obi = __shfl_xor(bi,  m, 64);
                if (ob > best || (ob == best && obi < bi)) { best = ob; bi = obi; }
            }
            if ((bi >> 2) == l16) mask |= 1u << (bi & 3);
            if (l16 == 0) {
                od[k] = d0[bi] + d1[bi];       // unbiased value
                int dh = (bi >> 3) - 4;
                int dw = (bi & 7) - 4;
                oi[k*3 + 0] = (float)t;
                oi[k*3 + 1] = (float)refl(qh + dh, HH);
                oi[k*3 + 2] = (float)refl(qxx*4 + dw, WW);
            }
        }
    }
}

extern "C" void kernel_launch(void* const* d_in, const int* in_sizes, int n_in,
                              void* d_out, int out_size, void* d_ws, size_t ws_size,
                              hipStream_t stream) {
    (void)in_sizes; (void)n_in; (void)d_ws; (void)ws_size; (void)out_size;
    const float* vid0 = (const float*)d_in[0];
    const float* vid1 = (const float*)d_in[1];
    float* out = (float*)d_out;
    nls_kernel<<<dim3(TT * NQ * (NQ / QPB)), dim3(256), 0, stream>>>(vid0, vid1, out);
}